// Round 8
// baseline (109.167 us; speedup 1.0000x reference)
//
#include <hip/hip_runtime.h>

typedef __attribute__((ext_vector_type(8))) short bf16x8;
typedef __attribute__((ext_vector_type(4))) float f32x4;
typedef __attribute__((ext_vector_type(16))) float f32x16;
typedef __attribute__((ext_vector_type(4))) float fl4;
typedef __attribute__((ext_vector_type(8))) unsigned short u16x8;
typedef __attribute__((ext_vector_type(4))) unsigned short u16x4;
typedef __attribute__((ext_vector_type(2))) int i32x2;
typedef __attribute__((ext_vector_type(4))) int i32x4;

#define MFMA16(A,B,C) __builtin_amdgcn_mfma_f32_16x16x32_bf16((A),(B),(C),0,0,0)
#define MFMA32(A,B,C) __builtin_amdgcn_mfma_f32_32x32x16_bf16((A),(B),(C),0,0,0)

__device__ __forceinline__ unsigned short f2bf_bits(float x) {
  union { float f; unsigned u; } v; v.f = x;
  unsigned r = v.u + 0x7fffu + ((v.u >> 16) & 1u);  // RTNE
  return (unsigned short)(r >> 16);
}

__device__ __forceinline__ void gload_lds16(const void* g, void* l) {
  __builtin_amdgcn_global_load_lds((const __attribute__((address_space(1))) void*)g,
                                   (__attribute__((address_space(3))) void*)l, 16, 0, 0);
}

// read one 16B MFMA fragment from a 128B-row LDS tile with XOR swizzle
__device__ __forceinline__ bf16x8 lds_frag(const char* base, int row, int bir) {
  int off = (row << 7) + bir;
  off ^= (row & 7) << 4;
  return *(const bf16x8*)(base + off);
}

// pack two f32 to packed bf16 (lo = a, hi = b), RTNE
__device__ __forceinline__ int cvtpk_bf16(float a, float b) {
  int r; asm("v_cvt_pk_bf16_f32 %0, %1, %2" : "=v"(r) : "v"(a), "v"(b)); return r;
}

// swap a's upper-lane-half with b's lower-lane-half (v_permlane32_swap_b32)
__device__ __forceinline__ void plswap(int& a, int& b) {
#if __has_builtin(__builtin_amdgcn_permlane32_swap)
  i32x2 r = __builtin_amdgcn_permlane32_swap(a, b, false, false);
  a = r[0]; b = r[1];
#else
  asm volatile("s_nop 1\n\tv_permlane32_swap_b32 %0, %1" : "+v"(a), "+v"(b));
#endif
}

// ---------------- elementwise fp32 -> bf16 ----------------
__global__ __launch_bounds__(256) void k_cvt(const float* __restrict__ src,
                                             unsigned short* __restrict__ dst, int n) {
  int i = (blockIdx.x * 256 + threadIdx.x) * 8;
  if (i >= n) return;
  fl4 a = *(const fl4*)(src + i);
  fl4 b = *(const fl4*)(src + i + 4);
  u16x8 o;
  o[0] = f2bf_bits(a[0]); o[1] = f2bf_bits(a[1]); o[2] = f2bf_bits(a[2]); o[3] = f2bf_bits(a[3]);
  o[4] = f2bf_bits(b[0]); o[5] = f2bf_bits(b[1]); o[6] = f2bf_bits(b[2]); o[7] = f2bf_bits(b[3]);
  *(u16x8*)(dst + i) = o;
}

// ---------------- mask -> additive exp2-domain bias: mb = m*7.2134752 - 12.9842554 ----------------
// ((1-m)*(-5.0) - 4.0) * log2(e)
__global__ __launch_bounds__(256) void k_mbias(const float* __restrict__ m,
                                               float* __restrict__ o) {
  int i = blockIdx.x * 256 + threadIdx.x;
  o[i] = fmaf(m[i], 7.2134752f, -12.9842554f);
}

// ---------------- transpose + convert: src [K=1024][NCOL] f32 -> dst [NCOL][1024] bf16 ----------------
__global__ __launch_bounds__(256) void k_tcvt(const float* __restrict__ src,
                                              unsigned short* __restrict__ dst, int NCOL) {
  __shared__ float tile[64][65];
  const int kt = blockIdx.y * 64, nt = blockIdx.x * 64;
  const int t = threadIdx.x;
  {
    int r = t >> 2, c0 = (t & 3) * 16;
    const float* s = src + (size_t)(kt + r) * NCOL + nt + c0;
    #pragma unroll
    for (int j = 0; j < 4; ++j) {
      fl4 v = *(const fl4*)(s + j * 4);
      tile[r][c0 + j * 4 + 0] = v[0]; tile[r][c0 + j * 4 + 1] = v[1];
      tile[r][c0 + j * 4 + 2] = v[2]; tile[r][c0 + j * 4 + 3] = v[3];
    }
  }
  __syncthreads();
  {
    int n = t >> 2, kc = (t & 3) * 16;
    unsigned short* d = dst + (size_t)(nt + n) * 1024 + kt + kc;
    u16x8 o0, o1;
    #pragma unroll
    for (int j = 0; j < 8; ++j) o0[j] = f2bf_bits(tile[kc + j][n]);
    #pragma unroll
    for (int j = 0; j < 8; ++j) o1[j] = f2bf_bits(tile[kc + 8 + j][n]);
    *(u16x8*)d = o0;
    *(u16x8*)(d + 8) = o1;
  }
}

// ---------------- bf16 GEMM: C[M][Ncols] = A[M][1024] * Bt[Ncols][1024]^T ----------------
template <int MODE>
__global__ __launch_bounds__(256) void k_gemm(const unsigned short* __restrict__ A,
                                              const unsigned short* __restrict__ Bt,
                                              unsigned short* __restrict__ qp,
                                              unsigned short* __restrict__ kp,
                                              unsigned short* __restrict__ vtp,
                                              const float* __restrict__ bias,
                                              float* __restrict__ outp) {
  __shared__ char lA[16384], lB[16384];
  const int tid = threadIdx.x, lane = tid & 63, w = tid >> 6;
  const int wm = w >> 1, wn = w & 1;
  const int m0 = blockIdx.y * 128, n0 = blockIdx.x * 128;
  const char* Ab = (const char*)A + (size_t)m0 * 2048;
  const char* Bb = (const char*)Bt + (size_t)n0 * 2048;

  f32x4 acc[4][4];
  #pragma unroll
  for (int mi = 0; mi < 4; ++mi)
    #pragma unroll
    for (int ni = 0; ni < 4; ++ni) acc[mi][ni] = f32x4{0.f, 0.f, 0.f, 0.f};

  for (int kt = 0; kt < 16; ++kt) {
    #pragma unroll
    for (int i = 0; i < 4; ++i) {
      int c = i * 256 + tid;
      int row = c >> 3, cc = c & 7, ccs = cc ^ (row & 7);
      char* dstA = lA + (i * 256 + w * 64) * 16;
      char* dstB = lB + (i * 256 + w * 64) * 16;
      gload_lds16(Ab + (size_t)row * 2048 + kt * 128 + ccs * 16, dstA);
      gload_lds16(Bb + (size_t)row * 2048 + kt * 128 + ccs * 16, dstB);
    }
    __syncthreads();
    #pragma unroll
    for (int ks = 0; ks < 2; ++ks) {
      bf16x8 af[4], bfv[4];
      #pragma unroll
      for (int mi = 0; mi < 4; ++mi)
        af[mi] = lds_frag(lA, wm * 64 + mi * 16 + (lane & 15), ks * 64 + ((lane >> 4) << 4));
      #pragma unroll
      for (int ni = 0; ni < 4; ++ni)
        bfv[ni] = lds_frag(lB, wn * 64 + ni * 16 + (lane & 15), ks * 64 + ((lane >> 4) << 4));
      #pragma unroll
      for (int mi = 0; mi < 4; ++mi)
        #pragma unroll
        for (int ni = 0; ni < 4; ++ni)
          acc[mi][ni] = MFMA16(af[mi], bfv[ni], acc[mi][ni]);
    }
    __syncthreads();
  }

  if (MODE == 0) {
    #pragma unroll
    for (int mi = 0; mi < 4; ++mi) {
      int row0 = m0 + wm * 64 + mi * 16 + ((lane >> 4) << 2);
      int bb = row0 >> 10, nn0 = row0 & 1023;
      #pragma unroll
      for (int ni = 0; ni < 4; ++ni) {
        int col = n0 + wn * 64 + ni * 16 + (lane & 15);
        int tt = col >> 10, rem = col & 1023, h = rem >> 6, d = rem & 63;
        f32x4 a = acc[mi][ni];
        if (tt == 2) {
          u16x4 pv;
          pv[0] = f2bf_bits(a[0]); pv[1] = f2bf_bits(a[1]);
          pv[2] = f2bf_bits(a[2]); pv[3] = f2bf_bits(a[3]);
          *(u16x4*)(vtp + (((size_t)(bb * 16 + h) * 64 + d) << 10) + nn0) = pv;
        } else {
          unsigned short* dst = (tt == 0) ? qp : kp;
          size_t base = ((size_t)(bb * 16 + h)) << 16;
          #pragma unroll
          for (int r = 0; r < 4; ++r)
            dst[base + (size_t)(nn0 + r) * 64 + d] = f2bf_bits(a[r]);
        }
      }
    }
  } else {
    #pragma unroll
    for (int mi = 0; mi < 4; ++mi) {
      int row0 = m0 + wm * 64 + mi * 16 + ((lane >> 4) << 2);
      #pragma unroll
      for (int ni = 0; ni < 4; ++ni) {
        int col = n0 + wn * 64 + ni * 16 + (lane & 15);
        float bv = bias[col];
        f32x4 a = acc[mi][ni];
        #pragma unroll
        for (int r = 0; r < 4; ++r)
          outp[(size_t)(row0 + r) * 1024 + col] = a[r] + bv;
      }
    }
  }
}

// ---------------- flash attention: in-block split-K, 64-key steps, two-window ILP ----------------
// 256 thr = 4 waves over 64 q-rows; wave-pair A keys 0-511, pair B keys 512-1023.
// 8 steps x 64 keys; per step two 32-key windows with independent QK acc chains,
// window-1 QK overlapping window-0 exp/PV. Mask bias precomputed (k_mbias), applied in exp fma.
// LDS 64KB: 2 buffers x [KA 8K | KB 8K | VA 8K | VB 8K].
//   K tile: 64 key-rows x 128B, chunk slot s at row r holds global d-chunk s^(r&7)
//   V tile: 64 d-rows  x 128B, chunk slot s at row r holds global key-chunk s^(r&7)
__global__ __launch_bounds__(256, 2) void k_attn(const unsigned short* __restrict__ qp,
                                                 const unsigned short* __restrict__ kp,
                                                 const unsigned short* __restrict__ vtp,
                                                 const float* __restrict__ mbias,
                                                 unsigned short* __restrict__ aop) {
  __shared__ __align__(16) char lds[65536];
  const int tid = threadIdx.x, lane = tid & 63, w = tid >> 6;
  const int hi = lane >> 5, lq = lane & 31;
  const int pair = w >> 1;
  // XCD swizzle: all 16 q-chunk blocks of a head on one XCD; 8 heads/XCD
  const int g = blockIdx.x;
  const int bh = (g & 7) * 8 + (g >> 7);
  const int qc = (g >> 3) & 15;
  const int b = bh >> 4, h = bh & 15;
  const char* kb = (const char*)(kp + ((size_t)bh << 16));
  const char* vb = (const char*)(vtp + ((size_t)bh << 16));
  const unsigned short* qh = qp + ((size_t)bh << 16);
  const float* mrow = mbias + b * 1024 + pair * 512;
  const int q0 = qc * 64 + (w & 1) * 32;

  // ---- hoisted staging offsets (chunk c = i*256+tid; i<4 -> K, else V) ----
  int koff[4], voff[4];
  #pragma unroll
  for (int i = 0; i < 4; ++i) {
    int idx = i * 256 + tid;
    int row = (idx >> 3) & 63, sx = (idx & 7) ^ (row & 7), pk = idx >> 9;
    koff[i] = pk * 65536 + row * 128 + sx * 16;               // + t*8192
    voff[i] = row * 2048 + pk * 1024 + sx * 16;               // + t*128
  }
  char* const dK = lds + tid * 16;            // + buf*32768 + i*4096
  char* const dV = lds + 16384 + tid * 16;    // + buf*32768 + i*4096
  const char* const myK = lds + pair * 8192;
  const char* const myV = lds + 16384 + pair * 8192;

  // ---- hoisted fragment offsets (window 0; win1: K +4096, V ^64) ----
  int kfo[4], vfo[2][2];
  #pragma unroll
  for (int dc = 0; dc < 4; ++dc)
    kfo[dc] = lq * 128 + ((((dc << 1) | hi) ^ (lq & 7)) << 4);
  #pragma unroll
  for (int ks = 0; ks < 2; ++ks)
    #pragma unroll
    for (int nb = 0; nb < 2; ++nb)
      vfo[ks][nb] = ((nb * 32 + lq) << 7) + ((((ks << 1) | hi) ^ (lq & 7)) << 4);

  // Q B-frags: B[kd = dc*16 + hi*8 + j][q = lq]
  bf16x8 qB[4];
  #pragma unroll
  for (int dc = 0; dc < 4; ++dc)
    qB[dc] = *(const bf16x8*)(qh + (q0 + lq) * 64 + dc * 16 + hi * 8);

  f32x16 O0, O1;
  #pragma unroll
  for (int i = 0; i < 16; ++i) { O0[i] = 0.f; O1[i] = 0.f; }
  float lsA = 0.f, lsB = 0.f;

#define STAGE(BUF, T)                                                          \
  do {                                                                         \
    _Pragma("unroll") for (int i = 0; i < 4; ++i) {                            \
      gload_lds16(kb + koff[i] + (T) * 8192, dK + (BUF) * 32768 + i * 4096);   \
      gload_lds16(vb + voff[i] + (T) * 128,  dV + (BUF) * 32768 + i * 4096);   \
    }                                                                          \
  } while (0)

#define QKW(ACC, KB2, WOFF)                                                    \
  do {                                                                         \
    _Pragma("unroll") for (int i2 = 0; i2 < 16; ++i2) (ACC)[i2] = 0.f;         \
    __builtin_amdgcn_s_setprio(1);                                             \
    _Pragma("unroll") for (int dc = 0; dc < 4; ++dc) {                         \
      bf16x8 kf = *(const bf16x8*)((KB2) + (WOFF) + kfo[dc]);                  \
      (ACC) = MFMA32(kf, qB[dc], (ACC));                                       \
    }                                                                          \
    __builtin_amdgcn_s_setprio(0);                                             \
  } while (0)

#define EXPW(P, ACC, MB)                                                       \
  do {                                                                         \
    _Pragma("unroll") for (int r = 0; r < 16; ++r) {                           \
      (P)[r] = exp2f(fmaf((ACC)[r], 0.18033688f, (MB)[r >> 2][r & 3]));        \
      if (r & 1) lsB += (P)[r]; else lsA += (P)[r];                            \
    }                                                                          \
  } while (0)

#define PACKPV(P, VB2, VX)                                                     \
  do {                                                                         \
    int X0 = cvtpk_bf16((P)[0], (P)[1]),   X1 = cvtpk_bf16((P)[2], (P)[3]);    \
    int Y0 = cvtpk_bf16((P)[4], (P)[5]),   Y1 = cvtpk_bf16((P)[6], (P)[7]);    \
    int Z0 = cvtpk_bf16((P)[8], (P)[9]),   Z1 = cvtpk_bf16((P)[10], (P)[11]);  \
    int W0 = cvtpk_bf16((P)[12], (P)[13]), W1 = cvtpk_bf16((P)[14], (P)[15]);  \
    plswap(X0, Y0); plswap(X1, Y1);                                            \
    plswap(Z0, W0); plswap(Z1, W1);                                            \
    i32x4 pa0v = {X0, X1, Y0, Y1};                                             \
    i32x4 pa1v = {Z0, Z1, W0, W1};                                             \
    const bf16x8 PA0 = __builtin_bit_cast(bf16x8, pa0v);                       \
    const bf16x8 PA1 = __builtin_bit_cast(bf16x8, pa1v);                       \
    bf16x8 v00 = *(const bf16x8*)((VB2) + (vfo[0][0] ^ (VX)));                 \
    bf16x8 v01 = *(const bf16x8*)((VB2) + (vfo[0][1] ^ (VX)));                 \
    bf16x8 v10 = *(const bf16x8*)((VB2) + (vfo[1][0] ^ (VX)));                 \
    bf16x8 v11 = *(const bf16x8*)((VB2) + (vfo[1][1] ^ (VX)));                 \
    __builtin_amdgcn_s_setprio(1);                                             \
    O0 = MFMA32(PA0, v00, O0);                                                 \
    O1 = MFMA32(PA0, v01, O1);                                                 \
    O0 = MFMA32(PA1, v10, O0);                                                 \
    O1 = MFMA32(PA1, v11, O1);                                                 \
    __builtin_amdgcn_s_setprio(0);                                             \
  } while (0)

#define STEP(BUF, T, LAST)                                                     \
  do {                                                                         \
    const char* Kb = myK + (BUF) * 32768;                                      \
    const char* Vb = myV + (BUF) * 32768;                                      \
    fl4 mw0[4], mw1[4];                                                        \
    _Pragma("unroll") for (int g4 = 0; g4 < 4; ++g4)                           \
      mw0[g4] = *(const fl4*)(mrow + (T) * 64 + g4 * 8 + hi * 4);              \
    if (!(LAST)) STAGE((BUF) ^ 1, (T) + 1);                                    \
    f32x16 acc0;                                                               \
    QKW(acc0, Kb, 0);                                                          \
    float p0[16];                                                              \
    EXPW(p0, acc0, mw0);                                                       \
    _Pragma("unroll") for (int g4 = 0; g4 < 4; ++g4)                           \
      mw1[g4] = *(const fl4*)(mrow + (T) * 64 + 32 + g4 * 8 + hi * 4);         \
    f32x16 acc1;                                                               \
    QKW(acc1, Kb, 4096);                                                       \
    PACKPV(p0, Vb, 0);                                                         \
    float p1[16];                                                              \
    EXPW(p1, acc1, mw1);                                                       \
    PACKPV(p1, Vb, 64);                                                        \
    __syncthreads();                                                           \
  } while (0)

  STAGE(0, 0);
  __syncthreads();
  #pragma unroll
  for (int tt = 0; tt < 4; ++tt) {
    STEP(0, 2 * tt, false);
    STEP(1, 2 * tt + 1, tt == 3);
  }
#undef STEP
#undef PACKPV
#undef EXPW
#undef QKW
#undef STAGE

  // ---- combine the two key-halves through LDS, then normalize + store ----
  float lsum = lsA + lsB;
  float tot = lsum + __shfl_xor(lsum, 32);
  float* fx = (float*)lds;
  if (pair == 1) {
    int base = (w - 2) * 64 * 34 + lane * 34;
    #pragma unroll
    for (int r = 0; r < 16; ++r) { fx[base + r] = O0[r]; fx[base + 16 + r] = O1[r]; }
    fx[base + 32] = tot;
  }
  __syncthreads();
  if (pair == 0) {
    int base = w * 64 * 34 + lane * 34;
    float invT = 1.0f / (tot + fx[base + 32]);
    #pragma unroll
    for (int r = 0; r < 16; ++r) {
      int qr = (r & 3) + 8 * (r >> 2) + 4 * hi;
      float iv = __shfl(invT, qr);
      float o0 = (O0[r] + fx[base + r]) * iv;
      float o1 = (O1[r] + fx[base + 16 + r]) * iv;
      size_t ob = (size_t)(b * 1024 + q0 + qr) * 1024 + h * 64 + lq;
      aop[ob] = f2bf_bits(o0);
      aop[ob + 32] = f2bf_bits(o1);
    }
  }
}

extern "C" void kernel_launch(void* const* d_in, const int* in_sizes, int n_in,
                              void* d_out, int out_size, void* d_ws, size_t ws_size,
                              hipStream_t stream) {
  const float* x     = (const float*)d_in[0];
  const float* mask  = (const float*)d_in[1];
  const float* wqkv  = (const float*)d_in[2];
  const float* wproj = (const float*)d_in[3];
  const float* bproj = (const float*)d_in[4];
  float* out = (float*)d_out;

  char* ws = (char*)d_ws;
  unsigned short* xb     = (unsigned short*)(ws);                 //  8 MB  x bf16 [4096][1024]
  unsigned short* wqkvt  = (unsigned short*)(ws + 8388608);       //  6 MB  W_qkv^T bf16 [3072][1024]
  unsigned short* wprojt = (unsigned short*)(ws + 14680064);      //  2 MB  W_proj^T bf16 [1024][1024]
  unsigned short* qbuf   = (unsigned short*)(ws + 16777216);      //  8 MB  q [B,H,N,D]
  unsigned short* kbuf   = (unsigned short*)(ws + 25165824);      //  8 MB  k [B,H,N,D]
  unsigned short* vtbuf  = (unsigned short*)(ws + 33554432);      //  8 MB  v^T [B,H,D,N]
  unsigned short* aobuf  = (unsigned short*)(ws + 41943040);      //  8 MB  attn out bf16 [4096][1024]
  float*          mbias  = (float*)(ws + 50331648);               // 16 KB  mask bias

  k_cvt<<<dim3(2048), dim3(256), 0, stream>>>(x, xb, 4194304);
  k_mbias<<<dim3(16), dim3(256), 0, stream>>>(mask, mbias);
  k_tcvt<<<dim3(48, 16), dim3(256), 0, stream>>>(wqkv, wqkvt, 3072);
  k_tcvt<<<dim3(16, 16), dim3(256), 0, stream>>>(wproj, wprojt, 1024);
  k_gemm<0><<<dim3(24, 32), dim3(256), 0, stream>>>(xb, wqkvt, qbuf, kbuf, vtbuf, nullptr, nullptr);
  k_attn<<<dim3(1024), dim3(256), 0, stream>>>(qbuf, kbuf, vtbuf, mbias, aobuf);
  k_gemm<1><<<dim3(8, 32), dim3(256), 0, stream>>>(aobuf, wprojt, nullptr, nullptr, nullptr, bproj, out);
}